// Round 2
// baseline (413.232 us; speedup 1.0000x reference)
//
#include <hip/hip_runtime.h>
#include <stdint.h>
#include <stddef.h>

// BitLinear on MI355X: out[m,o] = sx[m] * sw * sum_i qx[m,i]*qw[o,i]
//   qx: per-row int8 absmax fake-quant of x, qw: ternary {-1,0,1} from absmean.
// Integer inner product is exact; only scales carry float rounding.

#define K_DIM 4096
#define M_DIM 8192
#define N_DIM 4096

typedef int v4i __attribute__((ext_vector_type(4)));

// ---------------- async global->LDS (16B per lane, wave-uniform LDS base) ----
__device__ __forceinline__ void async_copy16(void* lds, const void* g) {
  __builtin_amdgcn_global_load_lds(
      (const __attribute__((address_space(1))) unsigned int*)g,
      (__attribute__((address_space(3))) unsigned int*)lds,
      16, 0, 0);
}

// ---------------- kernel 1: per-block partial sums of |w| (double) ----------
__global__ void k_wsum(const float* __restrict__ w, double* __restrict__ partials) {
  const float4* w4 = (const float4*)w;
  int tid = blockIdx.x * 256 + threadIdx.x;          // 262144 threads
  double s = 0.0;
  for (int i = tid; i < 4194304; i += 262144) {      // 16 iters
    float4 v = w4[i];
    s += (double)fabsf(v.x) + (double)fabsf(v.y) +
         (double)fabsf(v.z) + (double)fabsf(v.w);
  }
  for (int off = 32; off > 0; off >>= 1) s += __shfl_down(s, off);
  __shared__ double lsum[4];
  int lane = threadIdx.x & 63, wid = threadIdx.x >> 6;
  if (lane == 0) lsum[wid] = s;
  __syncthreads();
  if (threadIdx.x == 0)
    partials[blockIdx.x] = lsum[0] + lsum[1] + lsum[2] + lsum[3];
}

// ---------------- kernel 1b: reduce partials -> float scale -----------------
__global__ void k_wscale(const double* __restrict__ partials, float* __restrict__ wscale) {
  double s = 0.0;
  for (int i = threadIdx.x; i < 1024; i += 256) s += partials[i];
  for (int off = 32; off > 0; off >>= 1) s += __shfl_down(s, off);
  __shared__ double lsum[4];
  int lane = threadIdx.x & 63, wid = threadIdx.x >> 6;
  if (lane == 0) lsum[wid] = s;
  __syncthreads();
  if (threadIdx.x == 0) {
    double tot = lsum[0] + lsum[1] + lsum[2] + lsum[3];
    *wscale = (float)(tot / 16777216.0);             // exact-ish mean(|w|)
  }
}

// ---------------- kernel 2: ternary-quantize weight -> int8 -----------------
__global__ void k_wq(const float* __restrict__ w, const float* __restrict__ wscale,
                     char* __restrict__ qw) {
  float d = *wscale + 1e-8f;                         // matches ref divisor
  const float4* w4 = (const float4*)w;
  int* q4 = (int*)qw;
  int tid = blockIdx.x * 256 + threadIdx.x;          // 2048*256 = 524288 threads
  for (int i = tid; i < 4194304; i += 524288) {      // 8 iters
    float4 v = w4[i];
    int a = (int)fmaxf(fminf(rintf(v.x / d), 1.f), -1.f);
    int b = (int)fmaxf(fminf(rintf(v.y / d), 1.f), -1.f);
    int c = (int)fmaxf(fminf(rintf(v.z / d), 1.f), -1.f);
    int e = (int)fmaxf(fminf(rintf(v.w / d), 1.f), -1.f);
    q4[i] = (a & 255) | ((b & 255) << 8) | ((c & 255) << 16) | ((e & 255) << 24);
  }
}

// ---------------- kernel 3: per-row activation quantize -> int8 + scale -----
__global__ void k_xq(const float* __restrict__ x, char* __restrict__ qx,
                     float* __restrict__ sx) {
  int row = blockIdx.x;                               // 8192 rows
  const float4* xr = (const float4*)(x + (size_t)row * K_DIM);
  float4 v[4];
  float m = 0.f;
#pragma unroll
  for (int c = 0; c < 4; c++) {
    v[c] = xr[threadIdx.x + c * 256];
    m = fmaxf(m, fmaxf(fmaxf(fabsf(v[c].x), fabsf(v[c].y)),
                       fmaxf(fabsf(v[c].z), fabsf(v[c].w))));
  }
  for (int off = 32; off > 0; off >>= 1) m = fmaxf(m, __shfl_down(m, off));
  __shared__ float lm[4];
  __shared__ float bscale;
  int lane = threadIdx.x & 63, wid = threadIdx.x >> 6;
  if (lane == 0) lm[wid] = m;
  __syncthreads();
  if (threadIdx.x == 0) {
    float mm = fmaxf(fmaxf(lm[0], lm[1]), fmaxf(lm[2], lm[3]));
    float sc = fmaxf(mm / 127.0f, 1e-8f);            // true division like ref
    bscale = sc;
    sx[row] = sc;
  }
  __syncthreads();
  float sc = bscale;
  int* q4 = (int*)(qx + (size_t)row * K_DIM);
#pragma unroll
  for (int c = 0; c < 4; c++) {
    int a = (int)fmaxf(fminf(rintf(v[c].x / sc), 127.f), -127.f);
    int b = (int)fmaxf(fminf(rintf(v[c].y / sc), 127.f), -127.f);
    int cc = (int)fmaxf(fminf(rintf(v[c].z / sc), 127.f), -127.f);
    int e = (int)fmaxf(fminf(rintf(v[c].w / sc), 127.f), -127.f);
    q4[threadIdx.x + c * 256] = (a & 255) | ((b & 255) << 8) | ((cc & 255) << 16) | ((e & 255) << 24);
  }
}

// ---------------- kernel 4: int8 MFMA GEMM, 256x256 tile, 4-deep pipeline ---
// 8 waves (2M x 4N), per-wave 128x64 output (8x4 frags of 16x16).
// BK = 64 bytes per K-tile (one mfma_i32_16x16x64_i8 K-chunk), 64 K-tiles.
// LDS: 4 circular buffers x (A 16KiB + B 16KiB) = 128 KiB.
// T3 fine-phase schedule (m201 template grafted onto the verified 4-deep
// skeleton): per K-tile, after the publish {vmcnt(8); s_barrier}, FOUR phases,
// each = {6 ds_read_b128 (one C-quadrant's frags) + 1 staging load ->
//         s_barrier -> lgkmcnt(0) -> setprio(1) + 8 MFMA + setprio(0) ->
//         s_barrier}.
// Counted vmcnt(8) per tile (never drains to 0 in main loop).
// T2 both-sides XOR swizzle (k16 ^= (row>>1)&3): linear LDS dest for the DMA,
// pre-swizzled GLOBAL source, swizzled ds_read. (0 bank conflicts measured.)
// Race-freedom (same invariants as the passing round-1 kernel):
//  - buf[t&3] read at iter t: its 4 DMA loads retired by vmcnt(8) (only tiles
//    t+1,t+2 outstanding, 8 loads) in EVERY wave, then s_barrier -> visible.
//  - staging loads of tile t+3 (one per phase) write buf[(t-1)&3]: every
//    wave's ds_reads of tile t-1 were lgkm-drained before its last phase-3
//    barrier of iter t-1, which precedes iter t's publish barrier. The extra
//    per-phase barriers only TIGHTEN ordering vs round 1.
__global__ __launch_bounds__(512, 2) void k_gemm(const char* __restrict__ qx,
                       const char* __restrict__ qw,
                       const float* __restrict__ sx,
                       const float* __restrict__ wscale,
                       float* __restrict__ out) {
  __shared__ char lds[4][32768];                 // [buf][A:0..16K | B:16K..32K]

  const int tid = threadIdx.x;
  const int lane = tid & 63;
  const int wave = tid >> 6;                     // 0..7
  const int wr = wave >> 2;                      // M-half 0/1
  const int wc = wave & 3;                       // N-quarter 0..3

  // XCD-aware bijective swizzle (512 wgs, 8 XCDs, 64 wgs per XCD chunk)
  const int wg = (blockIdx.x & 7) * 64 + (blockIdx.x >> 3);
  const int bm = wg >> 4;                        // 32 M-tiles
  const int bn = wg & 15;                        // 16 N-tiles
  const int rowBase = bm * 256;
  const int colBase = bn * 256;

  // ---- staging addressing: LDS linear (tid*16), global source pre-swizzled
  const int rl = tid >> 2;                       // row 0..127 within half-tile
  const int kswz = (((tid & 3) ^ ((rl >> 1) & 3)) << 4);
  const char* gA0 = qx + (size_t)(rowBase + rl) * K_DIM + kswz;
  const char* gA1 = gA0 + (size_t)128 * K_DIM;   // rows 128..255 (same swizzle)
  const char* gB0 = qw + (size_t)(colBase + rl) * K_DIM + kswz;
  const char* gB1 = gB0 + (size_t)128 * K_DIM;
  const int dOff = wave << 10;                   // wave-uniform LDS base

  // ---- compute-phase read offsets (same XOR involution on the k16 column)
  const int sR = ((lane & 15) >> 1) & 3;
  const int kro = (((lane >> 4) ^ sR) << 4);
  const int aOff = ((wr << 7) + (lane & 15)) * 64 + kro;          // A region
  const int bOff = 16384 + ((wc << 6) + (lane & 15)) * 64 + kro;  // B region

  v4i acc[8][4] = {};

  auto STAGE1 = [&](int t, int q) {              // q-th staging load of tile t
    char* b = &lds[t & 3][0];
    const size_t ko = (size_t)t << 6;            // t*64 bytes along K
    if (q == 0)      async_copy16(b + dOff,         gA0 + ko);  // A rows 0..127
    else if (q == 1) async_copy16(b + 8192 + dOff,  gA1 + ko);  // A rows 128..255
    else if (q == 2) async_copy16(b + 16384 + dOff, gB0 + ko);  // B rows 0..127
    else             async_copy16(b + 24576 + dOff, gB1 + ko);  // B rows 128..255
  };

  // prologue: 3 tiles in flight (12 per-wave loads)
#pragma unroll
  for (int q = 0; q < 4; ++q) STAGE1(0, q);
#pragma unroll
  for (int q = 0; q < 4; ++q) STAGE1(1, q);
#pragma unroll
  for (int q = 0; q < 4; ++q) STAGE1(2, q);

  // main loop: 61 iters, stages t+3 (1 load/phase), vmcnt never below 8
  for (int t = 0; t < 61; ++t) {
    asm volatile("s_waitcnt vmcnt(8)" ::: "memory");   // tile t landed
    __builtin_amdgcn_s_barrier();                      // publish tile t
    const char* b = &lds[t & 3][0];
#pragma unroll
    for (int q = 0; q < 4; ++q) {                      // 4 phases
      const int mh = q >> 1, nh = q & 1;               // C-quadrant
      v4i af[4], bf[2];
#pragma unroll
      for (int j = 0; j < 4; ++j)
        af[j] = *(const v4i*)(b + aOff + (mh * 4 + j) * 1024);
#pragma unroll
      for (int i = 0; i < 2; ++i)
        bf[i] = *(const v4i*)(b + bOff + (nh * 2 + i) * 1024);
      STAGE1(t + 3, q);                                // -> buf[(t-1)&3]
      asm volatile("" ::: "memory");                   // keep reads pre-barrier
      __builtin_amdgcn_s_barrier();
      asm volatile("s_waitcnt lgkmcnt(0)" ::: "memory");
      __builtin_amdgcn_s_setprio(1);
#pragma unroll
      for (int j = 0; j < 4; ++j)
#pragma unroll
        for (int i = 0; i < 2; ++i)
          acc[mh * 4 + j][nh * 2 + i] = __builtin_amdgcn_mfma_i32_16x16x64_i8(
              af[j], bf[i], acc[mh * 4 + j][nh * 2 + i], 0, 0, 0);
      __builtin_amdgcn_s_setprio(0);
      __builtin_amdgcn_s_barrier();
    }
  }

  // tail: tiles 61,62,63 — no staging, vmcnt drains 8 -> 4 -> 0
#pragma unroll
  for (int e = 0; e < 3; ++e) {
    const int t = 61 + e;
    if (e == 0)      asm volatile("s_waitcnt vmcnt(8)" ::: "memory");
    else if (e == 1) asm volatile("s_waitcnt vmcnt(4)" ::: "memory");
    else             asm volatile("s_waitcnt vmcnt(0)" ::: "memory");
    __builtin_amdgcn_s_barrier();
    const char* b = &lds[t & 3][0];
#pragma unroll
    for (int q = 0; q < 4; ++q) {
      const int mh = q >> 1, nh = q & 1;
      v4i af[4], bf[2];
#pragma unroll
      for (int j = 0; j < 4; ++j)
        af[j] = *(const v4i*)(b + aOff + (mh * 4 + j) * 1024);
#pragma unroll
      for (int i = 0; i < 2; ++i)
        bf[i] = *(const v4i*)(b + bOff + (nh * 2 + i) * 1024);
      asm volatile("" ::: "memory");
      __builtin_amdgcn_s_barrier();
      asm volatile("s_waitcnt lgkmcnt(0)" ::: "memory");
      __builtin_amdgcn_s_setprio(1);
#pragma unroll
      for (int j = 0; j < 4; ++j)
#pragma unroll
        for (int i = 0; i < 2; ++i)
          acc[mh * 4 + j][nh * 2 + i] = __builtin_amdgcn_mfma_i32_16x16x64_i8(
              af[j], bf[i], acc[mh * 4 + j][nh * 2 + i], 0, 0, 0);
      __builtin_amdgcn_s_setprio(0);
      __builtin_amdgcn_s_barrier();
    }
  }

  // epilogue: C/D 16x16 layout col=lane&15, row=(lane>>4)*4+reg
  const float swv = *wscale;
  const int col0 = colBase + (wc << 6) + (lane & 15);
  const int row0 = rowBase + (wr << 7) + ((lane >> 4) << 2);
#pragma unroll
  for (int m = 0; m < 8; ++m) {
#pragma unroll
    for (int r = 0; r < 4; ++r) {
      const int row = row0 + m * 16 + r;
      const float s = sx[row] * swv;
#pragma unroll
      for (int n = 0; n < 4; ++n)
        out[(size_t)row * N_DIM + col0 + n * 16] = (float)acc[m][n][r] * s;
    }
  }
}

// ---------------- launcher ---------------------------------------------------
extern "C" void kernel_launch(void* const* d_in, const int* in_sizes, int n_in,
                              void* d_out, int out_size, void* d_ws, size_t ws_size,
                              hipStream_t stream) {
  const float* x = (const float*)d_in[0];   // [2,4096,4096]
  const float* w = (const float*)d_in[1];   // [4096,4096]
  float* out = (float*)d_out;               // [2,4096,4096]
  char* ws = (char*)d_ws;

  // ws layout (needs ~48.1 MiB):
  double* partials = (double*)ws;                  // 1024 doubles  @ 0
  float* wscale    = (float*)(ws + 8192);          // 1 float       @ 8192
  float* sx        = (float*)(ws + 8448);          // 8192 floats   @ 8448
  char*  qw        = ws + 41472;                   // 16 MiB        @ 41472
  char*  qx        = ws + 41472 + 16777216;        // 32 MiB

  k_wsum  <<<1024, 256, 0, stream>>>(w, partials);
  k_wscale<<<   1, 256, 0, stream>>>(partials, wscale);
  k_wq    <<<2048, 256, 0, stream>>>(w, wscale, qw);
  k_xq    <<<8192, 256, 0, stream>>>(x, qx, sx);
  k_gemm  <<<32 * 16, 512, 0, stream>>>(qx, qw, sx, wscale, out);
}

// Round 3
// 389.010 us; speedup vs baseline: 1.0623x; 1.0623x over previous
//
#include <hip/hip_runtime.h>
#include <stdint.h>
#include <stddef.h>

// BitLinear on MI355X: out[m,o] = sx[m] * sw * sum_i qx[m,i]*qw[o,i]
//   qx: per-row int8 absmax fake-quant of x, qw: ternary {-1,0,1} from absmean.
// Integer inner product is exact; only scales carry float rounding.

#define K_DIM 4096
#define M_DIM 8192
#define N_DIM 4096

typedef int v4i __attribute__((ext_vector_type(4)));

// ---------------- async global->LDS (16B per lane, wave-uniform LDS base) ----
__device__ __forceinline__ void async_copy16(void* lds, const void* g) {
  __builtin_amdgcn_global_load_lds(
      (const __attribute__((address_space(1))) unsigned int*)g,
      (__attribute__((address_space(3))) unsigned int*)lds,
      16, 0, 0);
}

// ---------------- kernel 1: per-block partial sums of |w| (double) ----------
__global__ void k_wsum(const float* __restrict__ w, double* __restrict__ partials) {
  const float4* w4 = (const float4*)w;
  int tid = blockIdx.x * 256 + threadIdx.x;          // 262144 threads
  double s = 0.0;
  for (int i = tid; i < 4194304; i += 262144) {      // 16 iters
    float4 v = w4[i];
    s += (double)fabsf(v.x) + (double)fabsf(v.y) +
         (double)fabsf(v.z) + (double)fabsf(v.w);
  }
  for (int off = 32; off > 0; off >>= 1) s += __shfl_down(s, off);
  __shared__ double lsum[4];
  int lane = threadIdx.x & 63, wid = threadIdx.x >> 6;
  if (lane == 0) lsum[wid] = s;
  __syncthreads();
  if (threadIdx.x == 0)
    partials[blockIdx.x] = lsum[0] + lsum[1] + lsum[2] + lsum[3];
}

// ---------------- kernel 1b: reduce partials -> float scale -----------------
__global__ void k_wscale(const double* __restrict__ partials, float* __restrict__ wscale) {
  double s = 0.0;
  for (int i = threadIdx.x; i < 1024; i += 256) s += partials[i];
  for (int off = 32; off > 0; off >>= 1) s += __shfl_down(s, off);
  __shared__ double lsum[4];
  int lane = threadIdx.x & 63, wid = threadIdx.x >> 6;
  if (lane == 0) lsum[wid] = s;
  __syncthreads();
  if (threadIdx.x == 0) {
    double tot = lsum[0] + lsum[1] + lsum[2] + lsum[3];
    *wscale = (float)(tot / 16777216.0);             // exact-ish mean(|w|)
  }
}

// ---------------- kernel 2: ternary-quantize weight -> int8 -----------------
__global__ void k_wq(const float* __restrict__ w, const float* __restrict__ wscale,
                     char* __restrict__ qw) {
  float d = *wscale + 1e-8f;                         // matches ref divisor
  const float4* w4 = (const float4*)w;
  int* q4 = (int*)qw;
  int tid = blockIdx.x * 256 + threadIdx.x;          // 2048*256 = 524288 threads
  for (int i = tid; i < 4194304; i += 524288) {      // 8 iters
    float4 v = w4[i];
    int a = (int)fmaxf(fminf(rintf(v.x / d), 1.f), -1.f);
    int b = (int)fmaxf(fminf(rintf(v.y / d), 1.f), -1.f);
    int c = (int)fmaxf(fminf(rintf(v.z / d), 1.f), -1.f);
    int e = (int)fmaxf(fminf(rintf(v.w / d), 1.f), -1.f);
    q4[i] = (a & 255) | ((b & 255) << 8) | ((c & 255) << 16) | ((e & 255) << 24);
  }
}

// ---------------- kernel 3: per-row activation quantize -> int8 + scale -----
__global__ void k_xq(const float* __restrict__ x, char* __restrict__ qx,
                     float* __restrict__ sx) {
  int row = blockIdx.x;                               // 8192 rows
  const float4* xr = (const float4*)(x + (size_t)row * K_DIM);
  float4 v[4];
  float m = 0.f;
#pragma unroll
  for (int c = 0; c < 4; c++) {
    v[c] = xr[threadIdx.x + c * 256];
    m = fmaxf(m, fmaxf(fmaxf(fabsf(v[c].x), fabsf(v[c].y)),
                       fmaxf(fabsf(v[c].z), fabsf(v[c].w))));
  }
  for (int off = 32; off > 0; off >>= 1) m = fmaxf(m, __shfl_down(m, off));
  __shared__ float lm[4];
  __shared__ float bscale;
  int lane = threadIdx.x & 63, wid = threadIdx.x >> 6;
  if (lane == 0) lm[wid] = m;
  __syncthreads();
  if (threadIdx.x == 0) {
    float mm = fmaxf(fmaxf(lm[0], lm[1]), fmaxf(lm[2], lm[3]));
    float sc = fmaxf(mm / 127.0f, 1e-8f);            // true division like ref
    bscale = sc;
    sx[row] = sc;
  }
  __syncthreads();
  float sc = bscale;
  int* q4 = (int*)(qx + (size_t)row * K_DIM);
#pragma unroll
  for (int c = 0; c < 4; c++) {
    int a = (int)fmaxf(fminf(rintf(v[c].x / sc), 127.f), -127.f);
    int b = (int)fmaxf(fminf(rintf(v[c].y / sc), 127.f), -127.f);
    int cc = (int)fmaxf(fminf(rintf(v[c].z / sc), 127.f), -127.f);
    int e = (int)fmaxf(fminf(rintf(v[c].w / sc), 127.f), -127.f);
    q4[threadIdx.x + c * 256] = (a & 255) | ((b & 255) << 8) | ((cc & 255) << 16) | ((e & 255) << 24);
  }
}

// ---------------- kernel 4: int8 MFMA GEMM, 256x256 tile --------------------
// Round-1 skeleton (proven: 139us, 0 bank conflicts) + reg-level software
// pipeline: LDS->reg fragment reads for tile t+1 issue during tile t's MFMAs.
//   iter t:  vmcnt(4)            -- own tile-(t+1) DMA landed
//            s_barrier           -- tile t+1 published to all waves
//            late-read af[4..7] of tile t       (4 ds_read_b128)
//            pre-read  bf[0..3], af[0..3] of tile t+1 -> NEXT named reg set
//            STAGE(t+3)          -- 4 DMA loads -> buf[(t-1)&3]
//            16 MFMA from PRE-READ regs (zero LDS dependence -> no stall)
//            16 MFMA from late reads (issued ~330cyc earlier, counted lgkm)
// Race-freedom (provable, not timing-based): every ds_read of buf[(t-1)&3]
// is lgkm-drained by its consuming MFMA within iter t-1, i.e. before that
// wave reaches barrier(t); STAGE(t+3) targets buf[(t-1)&3] and issues only
// after barrier(t). DMA depth: STAGE(t+3) has ~2 full iterations (>3000cyc)
// to land before iter (t+2)'s vmcnt(4) -- covers worst-case ~900cyc HBM miss.
// Round-2 post-mortem: fine 4-phase split regressed (163us) -- 8-MFMA phases
// against 2 barriers + full lgkmcnt(0) drain each. Do NOT re-add per-phase
// barriers; the pipeline here hides latency without any lgkm drain.
// Reg double-buffer uses NAMED sets A/B + 2x unroll (rule #20: runtime index
// -> scratch).
__global__ __launch_bounds__(512, 2) void k_gemm(const char* __restrict__ qx,
                       const char* __restrict__ qw,
                       const float* __restrict__ sx,
                       const float* __restrict__ wscale,
                       float* __restrict__ out) {
  __shared__ char lds[4][32768];                 // [buf][A:0..16K | B:16K..32K]

  const int tid = threadIdx.x;
  const int lane = tid & 63;
  const int wave = tid >> 6;                     // 0..7
  const int wr = wave >> 2;                      // M-half 0/1
  const int wc = wave & 3;                       // N-quarter 0..3

  // XCD-aware bijective swizzle (512 wgs, 8 XCDs, 64 wgs per XCD chunk)
  const int wg = (blockIdx.x & 7) * 64 + (blockIdx.x >> 3);
  const int bm = wg >> 4;                        // 32 M-tiles
  const int bn = wg & 15;                        // 16 N-tiles
  const int rowBase = bm * 256;
  const int colBase = bn * 256;

  // ---- staging addressing: LDS linear (tid*16), global source pre-swizzled
  const int rl = tid >> 2;                       // row 0..127 within half-tile
  const int kswz = (((tid & 3) ^ ((rl >> 1) & 3)) << 4);
  const char* gA0 = qx + (size_t)(rowBase + rl) * K_DIM + kswz;
  const char* gA1 = gA0 + (size_t)128 * K_DIM;   // rows 128..255 (same swizzle)
  const char* gB0 = qw + (size_t)(colBase + rl) * K_DIM + kswz;
  const char* gB1 = gB0 + (size_t)128 * K_DIM;
  const int dOff = wave << 10;                   // wave-uniform LDS base

  // ---- compute-phase read offsets (same XOR involution on the k16 column)
  const int sR = ((lane & 15) >> 1) & 3;
  const int kro = (((lane >> 4) ^ sR) << 4);
  const int aOff = ((wr << 7) + (lane & 15)) * 64 + kro;          // A region
  const int bOff = 16384 + ((wc << 6) + (lane & 15)) * 64 + kro;  // B region

  v4i acc[8][4] = {};

  auto STAGE = [&](int t) {
    char* b = &lds[t & 3][0];
    const size_t ko = (size_t)t << 6;            // t*64 bytes along K
    async_copy16(b + dOff,         gA0 + ko);    // A rows   0..127
    async_copy16(b + 8192 + dOff,  gA1 + ko);    // A rows 128..255
    async_copy16(b + 16384 + dOff, gB0 + ko);    // B rows   0..127
    async_copy16(b + 24576 + dOff, gB1 + ko);    // B rows 128..255
  };

  // named pre-read fragment sets (A = even tiles, B = odd tiles)
  v4i afA[4], bfA[4], afB[4], bfB[4];

  // pre-read first-half fragments of tile T into the given named set
#define PRE_READ(T, AF, BF)                                                  \
  {                                                                          \
    const char* bx_ = &lds[(T) & 3][0];                                      \
    _Pragma("unroll") for (int j_ = 0; j_ < 4; ++j_)                         \
        BF[j_] = *(const v4i*)(bx_ + bOff + j_ * 1024);                      \
    _Pragma("unroll") for (int j_ = 0; j_ < 4; ++j_)                         \
        AF[j_] = *(const v4i*)(bx_ + aOff + j_ * 1024);                      \
  }

  // one full pipeline iteration for tile T (consumes CURAF/CURBF, fills NXT)
#define FULL_ITER(T, CURAF, CURBF, NXTAF, NXTBF, DO_STAGE, VMC)              \
  {                                                                          \
    asm volatile("s_waitcnt vmcnt(" #VMC ")" ::: "memory");                  \
    __builtin_amdgcn_s_barrier();                                            \
    asm volatile("" ::: "memory");                                           \
    const char* bc_ = &lds[(T) & 3][0];                                      \
    v4i afL_[4];                                                             \
    _Pragma("unroll") for (int j_ = 0; j_ < 4; ++j_)                         \
        afL_[j_] = *(const v4i*)(bc_ + aOff + (4 + j_) * 1024);              \
    PRE_READ((T) + 1, NXTAF, NXTBF);                                         \
    if (DO_STAGE) STAGE((T) + 3);                                            \
    asm volatile("" ::: "memory");                                           \
    __builtin_amdgcn_s_setprio(1);                                           \
    _Pragma("unroll") for (int m_ = 0; m_ < 4; ++m_)                         \
        _Pragma("unroll") for (int n_ = 0; n_ < 4; ++n_)                     \
            acc[m_][n_] = __builtin_amdgcn_mfma_i32_16x16x64_i8(             \
                CURAF[m_], CURBF[n_], acc[m_][n_], 0, 0, 0);                 \
    _Pragma("unroll") for (int m_ = 0; m_ < 4; ++m_)                         \
        _Pragma("unroll") for (int n_ = 0; n_ < 4; ++n_)                     \
            acc[4 + m_][n_] = __builtin_amdgcn_mfma_i32_16x16x64_i8(         \
                afL_[m_], CURBF[n_], acc[4 + m_][n_], 0, 0, 0);              \
    __builtin_amdgcn_s_setprio(0);                                           \
  }

  // prologue: 3 tiles in flight (12 per-wave loads), pre-read tile 0
  STAGE(0); STAGE(1); STAGE(2);
  asm volatile("s_waitcnt vmcnt(8)" ::: "memory");   // tile 0 landed
  __builtin_amdgcn_s_barrier();                      // publish tile 0
  asm volatile("" ::: "memory");
  PRE_READ(0, afA, bfA);

  // main loop: tiles 0..59 in pairs (stages 3..62)
  for (int tp = 0; tp < 30; ++tp) {
    const int t = tp * 2;
    FULL_ITER(t,     afA, bfA, afB, bfB, 1, 4);      // even tile from set A
    FULL_ITER(t + 1, afB, bfB, afA, bfA, 1, 4);      // odd  tile from set B
  }
  // tile 60: last stage (63)
  FULL_ITER(60, afA, bfA, afB, bfB, 1, 4);
  // tiles 61,62: no staging, drain 8 -> 4 -> 0
  FULL_ITER(61, afB, bfB, afA, bfA, 0, 4);
  FULL_ITER(62, afA, bfA, afB, bfB, 0, 0);
  // tile 63: published by iter-62 barrier; late reads + compute only
  {
    const char* bc_ = &lds[63 & 3][0];
    v4i afL_[4];
#pragma unroll
    for (int j_ = 0; j_ < 4; ++j_)
      afL_[j_] = *(const v4i*)(bc_ + aOff + (4 + j_) * 1024);
    __builtin_amdgcn_s_setprio(1);
#pragma unroll
    for (int m_ = 0; m_ < 4; ++m_)
#pragma unroll
      for (int n_ = 0; n_ < 4; ++n_)
        acc[m_][n_] = __builtin_amdgcn_mfma_i32_16x16x64_i8(
            afB[m_], bfB[n_], acc[m_][n_], 0, 0, 0);
#pragma unroll
    for (int m_ = 0; m_ < 4; ++m_)
#pragma unroll
      for (int n_ = 0; n_ < 4; ++n_)
        acc[4 + m_][n_] = __builtin_amdgcn_mfma_i32_16x16x64_i8(
            afL_[m_], bfB[n_], acc[4 + m_][n_], 0, 0, 0);
    __builtin_amdgcn_s_setprio(0);
  }
#undef FULL_ITER
#undef PRE_READ

  // epilogue: C/D 16x16 layout col=lane&15, row=(lane>>4)*4+reg
  const float swv = *wscale;
  const int col0 = colBase + (wc << 6) + (lane & 15);
  const int row0 = rowBase + (wr << 7) + ((lane >> 4) << 2);
#pragma unroll
  for (int m = 0; m < 8; ++m) {
#pragma unroll
    for (int r = 0; r < 4; ++r) {
      const int row = row0 + m * 16 + r;
      const float s = sx[row] * swv;
#pragma unroll
      for (int n = 0; n < 4; ++n)
        out[(size_t)row * N_DIM + col0 + n * 16] = (float)acc[m][n][r] * s;
    }
  }
}

// ---------------- launcher ---------------------------------------------------
extern "C" void kernel_launch(void* const* d_in, const int* in_sizes, int n_in,
                              void* d_out, int out_size, void* d_ws, size_t ws_size,
                              hipStream_t stream) {
  const float* x = (const float*)d_in[0];   // [2,4096,4096]
  const float* w = (const float*)d_in[1];   // [4096,4096]
  float* out = (float*)d_out;               // [2,4096,4096]
  char* ws = (char*)d_ws;

  // ws layout (needs ~48.1 MiB):
  double* partials = (double*)ws;                  // 1024 doubles  @ 0
  float* wscale    = (float*)(ws + 8192);          // 1 float       @ 8192
  float* sx        = (float*)(ws + 8448);          // 8192 floats   @ 8448
  char*  qw        = ws + 41472;                   // 16 MiB        @ 41472
  char*  qx        = ws + 41472 + 16777216;        // 32 MiB

  k_wsum  <<<1024, 256, 0, stream>>>(w, partials);
  k_wscale<<<   1, 256, 0, stream>>>(partials, wscale);
  k_wq    <<<2048, 256, 0, stream>>>(w, wscale, qw);
  k_xq    <<<8192, 256, 0, stream>>>(x, qx, sx);
  k_gemm  <<<32 * 16, 512, 0, stream>>>(qx, qw, sx, wscale, out);
}